// Round 1
// baseline (531.980 us; speedup 1.0000x reference)
//
#include <hip/hip_runtime.h>

typedef __bf16 bf16;
typedef bf16  bf16x8 __attribute__((ext_vector_type(8)));
typedef bf16  bf16x2 __attribute__((ext_vector_type(2)));
typedef float f32x4  __attribute__((ext_vector_type(4)));

#define AS1 __attribute__((address_space(1)))
#define AS3 __attribute__((address_space(3)))

// ---------------- fp32 -> bf16 convert (memory-bound) ----------------
__global__ __launch_bounds__(256) void cvt_f32_bf16(const float* __restrict__ in,
                                                    bf16* __restrict__ out, int n8) {
  int i = blockIdx.x * blockDim.x + threadIdx.x;
  if (i >= n8) return;
  const float4* p = (const float4*)in + (size_t)i * 2;
  float4 a = p[0], b = p[1];
  bf16x8 o;
  o[0] = (bf16)a.x; o[1] = (bf16)a.y; o[2] = (bf16)a.z; o[3] = (bf16)a.w;
  o[4] = (bf16)b.x; o[5] = (bf16)b.y; o[6] = (bf16)b.z; o[7] = (bf16)b.w;
  *((bf16x8*)out + i) = o;
}

// ---------------- NT GEMM: C[M,N] = A[M,K] * B[N,K]^T, bf16 in, fp32 acc ---------
// 128x128 tile, BK=32, 4 waves, each wave 64x64 (4x4 MFMA 16x16x32).
// Staging: global_load_lds width=16; LDS contiguous (lane-order), XOR-4 k-chunk
// swizzle applied on the GLOBAL address so ds_read_b128 is ~2-way (free).
template <int OUTF32>
__global__ __launch_bounds__(256, 2)
void gemm_bt(const bf16* __restrict__ A, const bf16* __restrict__ B,
             float* __restrict__ Cf, bf16* __restrict__ Cb,
             int M, int N, int K) {
  __shared__ bf16 Asl[128 * 32];
  __shared__ bf16 Bsl[128 * 32];
  const int tid  = threadIdx.x;
  const int lane = tid & 63, wave = tid >> 6;
  const int quad = lane >> 4, col = lane & 15;
  const int m0 = blockIdx.x * 128, n0 = blockIdx.y * 128;
  const int wr = wave >> 1, wc = wave & 1;

  f32x4 acc[4][4];
  const f32x4 fz = {0.f, 0.f, 0.f, 0.f};
#pragma unroll
  for (int i = 0; i < 4; ++i)
#pragma unroll
    for (int j = 0; j < 4; ++j) acc[i][j] = fz;

  const int srow = lane >> 2;  // row within 16-row chunk
  const int sk   = lane & 3;   // 16B slot within 64B row

  for (int k0 = 0; k0 < K; k0 += 32) {
    __syncthreads();  // previous iter's LDS reads done
#pragma unroll
    for (int r = 0; r < 2; ++r) {
      const int c      = wave * 2 + r;       // 16-row chunk id (0..7)
      const int row    = c * 16 + srow;      // tile row
      const int gchunk = sk ^ (row & 3);     // swizzled global k-chunk
      const bf16* ga = A + (size_t)(m0 + row) * K + k0 + gchunk * 8;
      const bf16* gb = B + (size_t)(n0 + row) * K + k0 + gchunk * 8;
      __builtin_amdgcn_global_load_lds((const AS1 void*)ga, (AS3 void*)(&Asl[c * 512]), 16, 0, 0);
      __builtin_amdgcn_global_load_lds((const AS1 void*)gb, (AS3 void*)(&Bsl[c * 512]), 16, 0, 0);
    }
    __syncthreads();  // barrier drains vmcnt -> staged data visible

    bf16x8 af[4], bfr[4];
#pragma unroll
    for (int i = 0; i < 4; ++i) {
      const int r = wr * 64 + i * 16 + col;
      af[i] = *(const bf16x8*)&Asl[r * 32 + ((quad ^ (col & 3)) * 8)];
    }
#pragma unroll
    for (int j = 0; j < 4; ++j) {
      const int r = wc * 64 + j * 16 + col;
      bfr[j] = *(const bf16x8*)&Bsl[r * 32 + ((quad ^ (col & 3)) * 8)];
    }
#pragma unroll
    for (int i = 0; i < 4; ++i)
#pragma unroll
      for (int j = 0; j < 4; ++j)
        acc[i][j] = __builtin_amdgcn_mfma_f32_16x16x32_bf16(af[i], bfr[j], acc[i][j], 0, 0, 0);
  }

  // epilogue: D[row=quad*4+reg][col=lane&15]  (verified m89/m91 layout)
#pragma unroll
  for (int i = 0; i < 4; ++i) {
#pragma unroll
    for (int j = 0; j < 4; ++j) {
      const int gm0 = m0 + wr * 64 + i * 16 + quad * 4;
      const int gn  = n0 + wc * 64 + j * 16 + col;
#pragma unroll
      for (int r = 0; r < 4; ++r) {
        const size_t idx = (size_t)(gm0 + r) * N + gn;
        if (OUTF32) Cf[idx] = acc[i][j][r];
        else        Cb[idx] = (bf16)acc[i][j][r];
      }
    }
  }
}

// ---------------- flash causal attention ----------------
// Q,K,V,Y: [B*S, E] bf16, head h occupies cols [h*64, h*64+64).
// Block = 4 waves; Q-tile 64 rows (wave w owns rows w*16..w*16+15); t-tiles of 32.
#define SQLEN 2048
#define EMB   1024
__global__ __launch_bounds__(256, 2)
void attn_flash(const bf16* __restrict__ Q, const bf16* __restrict__ K,
                const bf16* __restrict__ V, bf16* __restrict__ Y) {
  __shared__ bf16 Qs[64][72];      // pad->144B stride: frag reads conflict-free
  __shared__ bf16 Ks[32][72];
  __shared__ bf16 VTs[64][40];     // V^T, pad->80B stride
  __shared__ bf16 Ps[4][16][40];   // per-wave P (C-layout -> A-layout round trip)

  const int tid  = threadIdx.x;
  const int lane = tid & 63, wave = tid >> 6;
  const int quad = lane >> 4, col = lane & 15;
  const int qt = blockIdx.x;   // 0..31
  const int h  = blockIdx.y;   // 0..15
  const int b  = blockIdx.z;   // 0..3
  const int q0 = qt * 64;
  const size_t rowBase = (size_t)b * SQLEN;
  const int hc = h * 64;

  // ---- load Q tile (64x64) ----
  {
    const int rr = tid >> 2;        // 0..63
    const int cc = tid & 3;         // 2x16B each
    const bf16* g = Q + (rowBase + q0 + rr) * EMB + hc;
    *(bf16x8*)&Qs[rr][cc * 16]     = *(const bf16x8*)&g[cc * 16];
    *(bf16x8*)&Qs[rr][cc * 16 + 8] = *(const bf16x8*)&g[cc * 16 + 8];
  }
  __syncthreads();

  // hoist loop-invariant Q fragments: A[m=lane&15][k=quad*8+j]
  bf16x8 qf0 = *(const bf16x8*)&Qs[wave * 16 + col][quad * 8];
  bf16x8 qf1 = *(const bf16x8*)&Qs[wave * 16 + col][32 + quad * 8];

  float mrow[4], lrow[4];
  f32x4 o[4];
  const f32x4 fz = {0.f, 0.f, 0.f, 0.f};
#pragma unroll
  for (int r = 0; r < 4; ++r) { mrow[r] = -INFINITY; lrow[r] = 0.f; }
#pragma unroll
  for (int d = 0; d < 4; ++d) o[d] = fz;

  const int ntt = qt * 2 + 2;  // t-tiles needed for causal coverage
  for (int tt = 0; tt < ntt; ++tt) {
    const int t0 = tt * 32;
    __syncthreads();  // prior iteration finished reading Ks/VTs

    // stage K tile (32x64), row-major
    {
      const int rr = tid >> 3;   // 0..31
      const int cc = tid & 7;    // 0..7
      *(bf16x8*)&Ks[rr][cc * 8] =
          *(const bf16x8*)&K[(rowBase + t0 + rr) * EMB + hc + cc * 8];
    }
    // stage V^T tile (64 d x 32 t), transposed scalar loads (coalesced on read)
    {
      const int d = tid & 63;
#pragma unroll
      for (int it = 0; it < 4; ++it) {
        const int tp = (tid >> 6) + it * 4;  // 0..15 (t-pair)
        bf16 v0 = V[(rowBase + t0 + 2 * tp)     * EMB + hc + d];
        bf16 v1 = V[(rowBase + t0 + 2 * tp + 1) * EMB + hc + d];
        bf16x2 pr = {v0, v1};
        *(bf16x2*)&VTs[d][2 * tp] = pr;
      }
    }
    __syncthreads();

    // ---- S = Q K^T over this 16q x 32t slab (per wave) ----
    f32x4 s0 = fz, s1 = fz;
    {
      bf16x8 kf00 = *(const bf16x8*)&Ks[col][quad * 8];
      bf16x8 kf01 = *(const bf16x8*)&Ks[col][32 + quad * 8];
      bf16x8 kf10 = *(const bf16x8*)&Ks[16 + col][quad * 8];
      bf16x8 kf11 = *(const bf16x8*)&Ks[16 + col][32 + quad * 8];
      s0 = __builtin_amdgcn_mfma_f32_16x16x32_bf16(qf0, kf00, s0, 0, 0, 0);
      s0 = __builtin_amdgcn_mfma_f32_16x16x32_bf16(qf1, kf01, s0, 0, 0, 0);
      s1 = __builtin_amdgcn_mfma_f32_16x16x32_bf16(qf0, kf10, s1, 0, 0, 0);
      s1 = __builtin_amdgcn_mfma_f32_16x16x32_bf16(qf1, kf11, s1, 0, 0, 0);
    }

    // ---- online softmax (rows live on (quad,reg); 16 t-cols across quad lanes) ----
    const int qbase = q0 + wave * 16 + quad * 4;
    float alpha[4];
#pragma unroll
    for (int r = 0; r < 4; ++r) {
      const int qg = qbase + r;
      float v0 = s0[r] * 0.125f;           // 1/sqrt(64)
      float v1 = s1[r] * 0.125f;
      if (t0 + col      > qg) v0 = -INFINITY;
      if (t0 + 16 + col > qg) v1 = -INFINITY;
      float mx = fmaxf(v0, v1);
#pragma unroll
      for (int off = 1; off < 16; off <<= 1) mx = fmaxf(mx, __shfl_xor(mx, off, 64));
      const float mnew = fmaxf(mrow[r], mx);
      const float a  = __expf(mrow[r] - mnew);   // first tile: exp(-inf)=0
      const float p0 = __expf(v0 - mnew);
      const float p1 = __expf(v1 - mnew);
      float rs = p0 + p1;
#pragma unroll
      for (int off = 1; off < 16; off <<= 1) rs += __shfl_xor(rs, off, 64);
      lrow[r] = lrow[r] * a + rs;
      mrow[r] = mnew;
      alpha[r] = a;
      // C-layout -> LDS (A-layout read below)
      Ps[wave][quad * 4 + r][col]      = (bf16)p0;
      Ps[wave][quad * 4 + r][16 + col] = (bf16)p1;
    }

    // rescale O
#pragma unroll
    for (int d = 0; d < 4; ++d)
#pragma unroll
      for (int r = 0; r < 4; ++r) o[d][r] *= alpha[r];

    __syncthreads();  // Ps visible (also keeps waves in lockstep)

    // ---- O += P V : A-frag = P[q=lane&15][t=quad*8+j], B-frag = V^T[d][t] ----
    bf16x8 pf = *(const bf16x8*)&Ps[wave][col][quad * 8];
#pragma unroll
    for (int d = 0; d < 4; ++d) {
      bf16x8 vf = *(const bf16x8*)&VTs[d * 16 + col][quad * 8];
      o[d] = __builtin_amdgcn_mfma_f32_16x16x32_bf16(pf, vf, o[d], 0, 0, 0);
    }
  }

  // ---- epilogue: Y = O / l ----
  const int qbase = q0 + wave * 16 + quad * 4;
#pragma unroll
  for (int d = 0; d < 4; ++d) {
#pragma unroll
    for (int r = 0; r < 4; ++r) {
      float val = o[d][r] / lrow[r];
      Y[(rowBase + qbase + r) * EMB + hc + d * 16 + col] = (bf16)val;
    }
  }
}

// ---------------- launcher ----------------
extern "C" void kernel_launch(void* const* d_in, const int* in_sizes, int n_in,
                              void* d_out, int out_size, void* d_ws, size_t ws_size,
                              hipStream_t stream) {
  const float* x  = (const float*)d_in[0];
  const float* Wq = (const float*)d_in[1];
  const float* Wk = (const float*)d_in[2];
  const float* Wv = (const float*)d_in[3];
  const float* Wo = (const float*)d_in[4];
  float* out = (float*)d_out;

  const size_t ME = 8192ull * 1024ull;  // activation elems
  const size_t WE = 1024ull * 1024ull;  // weight elems
  bf16* ws  = (bf16*)d_ws;
  bf16* xb  = ws;
  bf16* wqb = xb + ME;
  bf16* wkb = wqb + WE;
  bf16* wvb = wkb + WE;
  bf16* wob = wvb + WE;
  bf16* Qb  = wob + WE;
  bf16* Kb  = Qb + ME;
  bf16* Vb  = Kb + ME;
  bf16* Yb  = Vb + ME;   // total 46.1M elems = 92.3 MB of d_ws

  cvt_f32_bf16<<<(int)(ME / 8 / 256), 256, 0, stream>>>(x, xb, (int)(ME / 8));
  cvt_f32_bf16<<<(int)(WE / 8 / 256), 256, 0, stream>>>(Wq, wqb, (int)(WE / 8));
  cvt_f32_bf16<<<(int)(WE / 8 / 256), 256, 0, stream>>>(Wk, wkb, (int)(WE / 8));
  cvt_f32_bf16<<<(int)(WE / 8 / 256), 256, 0, stream>>>(Wv, wvb, (int)(WE / 8));
  cvt_f32_bf16<<<(int)(WE / 8 / 256), 256, 0, stream>>>(Wo, wob, (int)(WE / 8));

  dim3 ggrid(8192 / 128, 1024 / 128);  // 64 x 8
  gemm_bt<0><<<ggrid, 256, 0, stream>>>(xb, wqb, nullptr, Qb, 8192, 1024, 1024);
  gemm_bt<0><<<ggrid, 256, 0, stream>>>(xb, wkb, nullptr, Kb, 8192, 1024, 1024);
  gemm_bt<0><<<ggrid, 256, 0, stream>>>(xb, wvb, nullptr, Vb, 8192, 1024, 1024);

  attn_flash<<<dim3(32, 16, 4), 256, 0, stream>>>(Qb, Kb, Vb, Yb);

  gemm_bt<1><<<ggrid, 256, 0, stream>>>(Yb, wob, out, nullptr, 8192, 1024, 1024);
}

// Round 2
// 336.552 us; speedup vs baseline: 1.5807x; 1.5807x over previous
//
#include <hip/hip_runtime.h>

typedef __bf16 bf16;
typedef bf16  bf16x8 __attribute__((ext_vector_type(8)));
typedef bf16  bf16x4 __attribute__((ext_vector_type(4)));
typedef short s16x4  __attribute__((ext_vector_type(4)));
typedef float f32x4  __attribute__((ext_vector_type(4)));

#define AS1 __attribute__((address_space(1)))
#define AS3 __attribute__((address_space(3)))

#define SQLEN 2048
#define EMB   1024

// ---------------- fp32 -> bf16 convert (memory-bound) ----------------
__global__ __launch_bounds__(256) void cvt_f32_bf16(const float* __restrict__ in,
                                                    bf16* __restrict__ out, int n8) {
  int i = blockIdx.x * blockDim.x + threadIdx.x;
  if (i >= n8) return;
  const float4* p = (const float4*)in + (size_t)i * 2;
  float4 a = p[0], b = p[1];
  bf16x8 o;
  o[0] = (bf16)a.x; o[1] = (bf16)a.y; o[2] = (bf16)a.z; o[3] = (bf16)a.w;
  o[4] = (bf16)b.x; o[5] = (bf16)b.y; o[6] = (bf16)b.z; o[7] = (bf16)b.w;
  *((bf16x8*)out + i) = o;
}

// ---------------- V transpose: Vb[b*2048+t][n] -> Vt[(b*1024+n)][t] ----------
__global__ __launch_bounds__(256) void transpose_v(const bf16* __restrict__ Vb,
                                                   bf16* __restrict__ Vt) {
  __shared__ bf16 T[64][72];
  const int b = blockIdx.z;
  const int t0 = blockIdx.x * 64, n0 = blockIdx.y * 64;
  const int r = threadIdx.x >> 3, c = threadIdx.x & 7;
#pragma unroll
  for (int i = 0; i < 2; ++i) {
    const int row = i * 32 + r;
    *(bf16x8*)&T[row][c * 8] =
        *(const bf16x8*)&Vb[((size_t)(b * SQLEN + t0 + row)) * EMB + n0 + c * 8];
  }
  __syncthreads();
#pragma unroll
  for (int i = 0; i < 2; ++i) {
    const int n = i * 32 + r;
    bf16x8 o;
#pragma unroll
    for (int j = 0; j < 8; ++j) o[j] = T[c * 8 + j][n];
    *(bf16x8*)&Vt[((size_t)(b * EMB + n0 + n)) * SQLEN + t0 + c * 8] = o;
  }
}

// ---------------- NT GEMM: C[M,N] = A[M,K] * B[N,K]^T, bf16 in, fp32 acc ---------
// 128x128 tile, BK=32, 4 waves, each wave 64x64 (4x4 MFMA 16x16x32).
template <int OUTF32>
__global__ __launch_bounds__(256, 2)
void gemm_bt(const bf16* __restrict__ A, const bf16* __restrict__ B,
             float* __restrict__ Cf, bf16* __restrict__ Cb,
             int M, int N, int K, float scale) {
  __shared__ bf16 Asl[128 * 32];
  __shared__ bf16 Bsl[128 * 32];
  const int tid  = threadIdx.x;
  const int lane = tid & 63, wave = tid >> 6;
  const int quad = lane >> 4, col = lane & 15;
  const int m0 = blockIdx.x * 128, n0 = blockIdx.y * 128;
  const int wr = wave >> 1, wc = wave & 1;

  f32x4 acc[4][4];
  const f32x4 fz = {0.f, 0.f, 0.f, 0.f};
#pragma unroll
  for (int i = 0; i < 4; ++i)
#pragma unroll
    for (int j = 0; j < 4; ++j) acc[i][j] = fz;

  const int srow = lane >> 2;  // row within 16-row chunk
  const int sk   = lane & 3;   // 16B slot within 64B row

  for (int k0 = 0; k0 < K; k0 += 32) {
    __syncthreads();
#pragma unroll
    for (int r = 0; r < 2; ++r) {
      const int c      = wave * 2 + r;
      const int row    = c * 16 + srow;
      const int gchunk = sk ^ (row & 3);
      const bf16* ga = A + (size_t)(m0 + row) * K + k0 + gchunk * 8;
      const bf16* gb = B + (size_t)(n0 + row) * K + k0 + gchunk * 8;
      __builtin_amdgcn_global_load_lds((const AS1 void*)ga, (AS3 void*)(&Asl[c * 512]), 16, 0, 0);
      __builtin_amdgcn_global_load_lds((const AS1 void*)gb, (AS3 void*)(&Bsl[c * 512]), 16, 0, 0);
    }
    __syncthreads();

    bf16x8 af[4], bfr[4];
#pragma unroll
    for (int i = 0; i < 4; ++i) {
      const int r = wr * 64 + i * 16 + col;
      af[i] = *(const bf16x8*)&Asl[r * 32 + ((quad ^ (col & 3)) * 8)];
    }
#pragma unroll
    for (int j = 0; j < 4; ++j) {
      const int r = wc * 64 + j * 16 + col;
      bfr[j] = *(const bf16x8*)&Bsl[r * 32 + ((quad ^ (col & 3)) * 8)];
    }
#pragma unroll
    for (int i = 0; i < 4; ++i)
#pragma unroll
      for (int j = 0; j < 4; ++j)
        acc[i][j] = __builtin_amdgcn_mfma_f32_16x16x32_bf16(af[i], bfr[j], acc[i][j], 0, 0, 0);
  }

#pragma unroll
  for (int i = 0; i < 4; ++i) {
#pragma unroll
    for (int j = 0; j < 4; ++j) {
      const int gm0 = m0 + wr * 64 + i * 16 + quad * 4;
      const int gn  = n0 + wc * 64 + j * 16 + col;
#pragma unroll
      for (int r = 0; r < 4; ++r) {
        const size_t idx = (size_t)(gm0 + r) * N + gn;
        if (OUTF32) Cf[idx] = acc[i][j][r] * scale;
        else        Cb[idx] = (bf16)(acc[i][j][r] * scale);
      }
    }
  }
}

// ---------------- flash causal attention, S^T formulation ----------------
// Q: [B*S, E] bf16, PRE-SCALED by 0.125*log2(e). K: [B*S, E]. Vt: [(b*1024+n), t].
// Block = 4 waves, Q-tile 64 (wave w owns q = q0+16w+col), t-tile 64.
// S^T = mfma32(kf, qf): D[row=t(quad*4+r)][col=q]. Softmax per lane (col=q):
// in-lane reduce + shfl_xor(16,32). P^T C-layout IS the k16 B-operand layout ->
// PV: O^T = mfma16(vf, pf) with no LDS round-trip for P.
__global__ __launch_bounds__(256, 4)
void attn_flash(const bf16* __restrict__ Q, const bf16* __restrict__ K,
                const bf16* __restrict__ Vt, bf16* __restrict__ Y) {
  __shared__ bf16 Qs[64 * 64];
  __shared__ bf16 Ks[64 * 64];
  __shared__ bf16 Vs[64 * 64];     // V^T tile: [d][t]
  __shared__ bf16 Ot[4][16 * 72];  // per-wave O transpose-out buffer

  const int tid  = threadIdx.x;
  const int lane = tid & 63, wave = tid >> 6;
  const int quad = lane >> 4, col = lane & 15;
  const int qt = 31 - blockIdx.x;  // longest blocks first
  const int h  = blockIdx.y;
  const int b  = blockIdx.z;
  const int q0 = qt * 64;
  const int hc = h * 64;
  const size_t rowBase = (size_t)b * SQLEN;

  const int srow8 = lane >> 3;          // staging row 0..7 within instr
  const int sch   = lane & 7;           // staging chunk pos
  const int gch   = sch ^ srow8;        // XOR-8 swizzled global chunk
  const int a7    = col & 7;            // read-side row&7

  // ---- stage Q tile (swizzled), hoist Q fragments ----
#pragma unroll
  for (int i = 0; i < 2; ++i) {
    const int rr = (wave * 2 + i) * 8 + srow8;
    const bf16* g = Q + (rowBase + q0 + rr) * EMB + hc + gch * 8;
    __builtin_amdgcn_global_load_lds((const AS1 void*)g, (AS3 void*)(&Qs[(wave * 2 + i) * 512]), 16, 0, 0);
  }
  __syncthreads();
  const bf16x8 qf0 = *(const bf16x8*)&Qs[(wave * 16 + col) * 64 + ((quad ^ a7) * 8)];
  const bf16x8 qf1 = *(const bf16x8*)&Qs[(wave * 16 + col) * 64 + (((quad ^ 4) ^ a7) * 8)];

  float m_i = -INFINITY, l_i = 0.f;
  f32x4 o[4];
  const f32x4 fz = {0.f, 0.f, 0.f, 0.f};
#pragma unroll
  for (int dd = 0; dd < 4; ++dd) o[dd] = fz;

  for (int tt = 0; tt <= qt; ++tt) {
    const int t0 = tt * 64;
    __syncthreads();  // prior iter done reading Ks/Vs
#pragma unroll
    for (int i = 0; i < 2; ++i) {
      const int rr = (wave * 2 + i) * 8 + srow8;
      const bf16* gk = K + (rowBase + t0 + rr) * EMB + hc + gch * 8;
      const bf16* gv = Vt + ((size_t)(b * EMB + hc + rr)) * SQLEN + t0 + gch * 8;
      __builtin_amdgcn_global_load_lds((const AS1 void*)gk, (AS3 void*)(&Ks[(wave * 2 + i) * 512]), 16, 0, 0);
      __builtin_amdgcn_global_load_lds((const AS1 void*)gv, (AS3 void*)(&Vs[(wave * 2 + i) * 512]), 16, 0, 0);
    }
    __syncthreads();  // staged data visible

    // ---- S^T slabs: s[sl] covers t in [16sl,16sl+16) x q (16) ----
    f32x4 s[4];
#pragma unroll
    for (int sl = 0; sl < 4; ++sl) {
      const bf16x8 kf0 = *(const bf16x8*)&Ks[(sl * 16 + col) * 64 + ((quad ^ a7) * 8)];
      const bf16x8 kf1 = *(const bf16x8*)&Ks[(sl * 16 + col) * 64 + (((quad ^ 4) ^ a7) * 8)];
      f32x4 z = fz;
      z = __builtin_amdgcn_mfma_f32_16x16x32_bf16(kf0, qf0, z, 0, 0, 0);
      s[sl] = __builtin_amdgcn_mfma_f32_16x16x32_bf16(kf1, qf1, z, 0, 0, 0);
    }

    if (tt == qt) {  // diagonal tile: mask t_local > q_local
      const int qloc = wave * 16 + col;
#pragma unroll
      for (int sl = 0; sl < 4; ++sl)
#pragma unroll
        for (int r = 0; r < 4; ++r)
          if (sl * 16 + quad * 4 + r > qloc) s[sl][r] = -INFINITY;
    }

    // ---- online softmax in exp2 domain (per-lane scalars) ----
    float mx = s[0][0];
#pragma unroll
    for (int sl = 0; sl < 4; ++sl)
#pragma unroll
      for (int r = 0; r < 4; ++r) mx = fmaxf(mx, s[sl][r]);
    mx = fmaxf(mx, __shfl_xor(mx, 16));
    mx = fmaxf(mx, __shfl_xor(mx, 32));
    const float mnew  = fmaxf(m_i, mx);
    const float alpha = __builtin_amdgcn_exp2f(m_i - mnew);
    float rs = 0.f;
    bf16x4 pb[4];
#pragma unroll
    for (int sl = 0; sl < 4; ++sl)
#pragma unroll
      for (int r = 0; r < 4; ++r) {
        const float p = __builtin_amdgcn_exp2f(s[sl][r] - mnew);
        rs += p;
        pb[sl][r] = (bf16)p;
      }
    rs += __shfl_xor(rs, 16);
    rs += __shfl_xor(rs, 32);
    l_i = l_i * alpha + rs;
    m_i = mnew;
#pragma unroll
    for (int dd = 0; dd < 4; ++dd) o[dd] *= alpha;

    // ---- O^T += V^T P^T via k16 MFMA; pf comes straight from registers ----
#pragma unroll
    for (int sl = 0; sl < 4; ++sl) {
      const s16x4 pf = __builtin_bit_cast(s16x4, pb[sl]);
      const int cch  = 2 * sl + (quad >> 1);   // 16B chunk of t-offset
      const int half = quad & 1;
#pragma unroll
      for (int dd = 0; dd < 4; ++dd) {
        const int row = dd * 16 + col;
        const bf16x4 vb = *(const bf16x4*)&Vs[row * 64 + ((cch ^ a7) * 8) + half * 4];
        o[dd] = __builtin_amdgcn_mfma_f32_16x16x16bf16_1k(
            __builtin_bit_cast(s16x4, vb), pf, o[dd], 0, 0, 0);
      }
    }
  }

  // ---- epilogue: O^T/l -> per-wave LDS transpose -> coalesced store ----
  const float rl = __builtin_amdgcn_rcpf(l_i);
#pragma unroll
  for (int dd = 0; dd < 4; ++dd) {
    bf16x4 ob;
#pragma unroll
    for (int r = 0; r < 4; ++r) ob[r] = (bf16)(o[dd][r] * rl);
    *(bf16x4*)&Ot[wave][col * 72 + dd * 16 + quad * 4] = ob;
  }
  __syncthreads();
#pragma unroll
  for (int i = 0; i < 2; ++i) {
    const int row = i * 8 + srow8;
    const bf16x8 v = *(const bf16x8*)&Ot[wave][row * 72 + sch * 8];
    *(bf16x8*)&Y[(rowBase + q0 + wave * 16 + row) * EMB + hc + sch * 8] = v;
  }
}

// ---------------- launcher ----------------
extern "C" void kernel_launch(void* const* d_in, const int* in_sizes, int n_in,
                              void* d_out, int out_size, void* d_ws, size_t ws_size,
                              hipStream_t stream) {
  const float* x  = (const float*)d_in[0];
  const float* Wq = (const float*)d_in[1];
  const float* Wk = (const float*)d_in[2];
  const float* Wv = (const float*)d_in[3];
  const float* Wo = (const float*)d_in[4];
  float* out = (float*)d_out;

  const size_t ME = 8192ull * 1024ull;
  const size_t WE = 1024ull * 1024ull;
  bf16* ws  = (bf16*)d_ws;
  bf16* xb  = ws;
  bf16* wqb = xb + ME;
  bf16* wkb = wqb + WE;
  bf16* wvb = wkb + WE;
  bf16* wob = wvb + WE;
  bf16* Qb  = wob + WE;
  bf16* Kb  = Qb + ME;
  bf16* Vb  = Kb + ME;
  bf16* Yb  = Vb + ME;   // 92.3 MB total
  bf16* Vtb = xb;        // Vt aliases xb (xb dead after the V-GEMM)

  cvt_f32_bf16<<<(int)(ME / 8 / 256), 256, 0, stream>>>(x, xb, (int)(ME / 8));
  cvt_f32_bf16<<<(int)(WE / 8 / 256), 256, 0, stream>>>(Wq, wqb, (int)(WE / 8));
  cvt_f32_bf16<<<(int)(WE / 8 / 256), 256, 0, stream>>>(Wk, wkb, (int)(WE / 8));
  cvt_f32_bf16<<<(int)(WE / 8 / 256), 256, 0, stream>>>(Wv, wvb, (int)(WE / 8));
  cvt_f32_bf16<<<(int)(WE / 8 / 256), 256, 0, stream>>>(Wo, wob, (int)(WE / 8));

  dim3 ggrid(8192 / 128, 1024 / 128);
  const float qscale = 0.125f * 1.4426950408889634f;  // fold 1/sqrt(64) and log2(e)
  gemm_bt<0><<<ggrid, 256, 0, stream>>>(xb, wqb, nullptr, Qb, 8192, 1024, 1024, qscale);
  gemm_bt<0><<<ggrid, 256, 0, stream>>>(xb, wkb, nullptr, Kb, 8192, 1024, 1024, 1.0f);
  gemm_bt<0><<<ggrid, 256, 0, stream>>>(xb, wvb, nullptr, Vb, 8192, 1024, 1024, 1.0f);

  transpose_v<<<dim3(32, 16, 4), 256, 0, stream>>>(Vb, Vtb);
  attn_flash<<<dim3(32, 16, 4), 256, 0, stream>>>(Qb, Kb, Vtb, Yb);

  gemm_bt<1><<<ggrid, 256, 0, stream>>>(Yb, wob, out, nullptr, 8192, 1024, 1024, 1.0f);
}

// Round 3
// 302.943 us; speedup vs baseline: 1.7560x; 1.1109x over previous
//
#include <hip/hip_runtime.h>

typedef __bf16 bf16;
typedef bf16  bf16x8 __attribute__((ext_vector_type(8)));
typedef bf16  bf16x4 __attribute__((ext_vector_type(4)));
typedef short s16x4  __attribute__((ext_vector_type(4)));
typedef float f32x4  __attribute__((ext_vector_type(4)));

#define AS1 __attribute__((address_space(1)))
#define AS3 __attribute__((address_space(3)))

#define SQLEN 2048
#define EMB   1024

// ---------------- fp32 -> bf16 convert (memory-bound) ----------------
__global__ __launch_bounds__(256) void cvt_f32_bf16(const float* __restrict__ in,
                                                    bf16* __restrict__ out, int n8) {
  int i = blockIdx.x * blockDim.x + threadIdx.x;
  if (i >= n8) return;
  const float4* p = (const float4*)in + (size_t)i * 2;
  float4 a = p[0], b = p[1];
  bf16x8 o;
  o[0] = (bf16)a.x; o[1] = (bf16)a.y; o[2] = (bf16)a.z; o[3] = (bf16)a.w;
  o[4] = (bf16)b.x; o[5] = (bf16)b.y; o[6] = (bf16)b.z; o[7] = (bf16)b.w;
  *((bf16x8*)out + i) = o;
}

// 4 weight matrices in one dispatch (blockIdx.y selects)
__global__ __launch_bounds__(256) void cvt_w4(const float* __restrict__ w0, const float* __restrict__ w1,
                                              const float* __restrict__ w2, const float* __restrict__ w3,
                                              bf16* o0, bf16* o1, bf16* o2, bf16* o3, int n8) {
  const float* in; bf16* out;
  switch (blockIdx.y) {
    case 0: in = w0; out = o0; break;
    case 1: in = w1; out = o1; break;
    case 2: in = w2; out = o2; break;
    default: in = w3; out = o3; break;
  }
  int i = blockIdx.x * blockDim.x + threadIdx.x;
  if (i >= n8) return;
  const float4* p = (const float4*)in + (size_t)i * 2;
  float4 a = p[0], b = p[1];
  bf16x8 o;
  o[0] = (bf16)a.x; o[1] = (bf16)a.y; o[2] = (bf16)a.z; o[3] = (bf16)a.w;
  o[4] = (bf16)b.x; o[5] = (bf16)b.y; o[6] = (bf16)b.z; o[7] = (bf16)b.w;
  *((bf16x8*)out + i) = o;
}

// ---------------- V transpose: Vb[b*2048+t][n] -> Vt[(b*1024+n)][t] ----------
__global__ __launch_bounds__(256) void transpose_v(const bf16* __restrict__ Vb,
                                                   bf16* __restrict__ Vt) {
  __shared__ bf16 T[64][72];
  const int b = blockIdx.z;
  const int t0 = blockIdx.x * 64, n0 = blockIdx.y * 64;
  const int r = threadIdx.x >> 3, c = threadIdx.x & 7;
#pragma unroll
  for (int i = 0; i < 2; ++i) {
    const int row = i * 32 + r;
    *(bf16x8*)&T[row][c * 8] =
        *(const bf16x8*)&Vb[((size_t)(b * SQLEN + t0 + row)) * EMB + n0 + c * 8];
  }
  __syncthreads();
#pragma unroll
  for (int i = 0; i < 2; ++i) {
    const int n = i * 32 + r;
    bf16x8 o;
#pragma unroll
    for (int j = 0; j < 8; ++j) o[j] = T[c * 8 + j][n];
    *(bf16x8*)&Vt[((size_t)(b * EMB + n0 + n)) * SQLEN + t0 + c * 8] = o;
  }
}

// ---------------- NT GEMM body: C[M,N] = A[M,K]*B[N,K]^T, dbuf single-barrier K-loop
// 128x128 tile, BK=32, 4 waves x (4x4) 16x16x32 MFMA. Prefetch tile it+1 is issued
// at the TOP of iter it -> in flight across the whole compute; ONE barrier/iter.
template <int OUTF32>
__device__ __forceinline__
void gemm_body(const bf16* __restrict__ A, const bf16* __restrict__ B,
               float* __restrict__ Cf, bf16* __restrict__ Cb,
               int M, int N, int K, float scale, bf16* Asl, bf16* Bsl) {
  const int tid  = threadIdx.x;
  const int lane = tid & 63, wave = tid >> 6;
  const int quad = lane >> 4, col = lane & 15;
  const int m0 = blockIdx.x * 128, n0 = blockIdx.y * 128;
  const int wr = wave >> 1, wc = wave & 1;

  f32x4 acc[4][4];
  const f32x4 fz = {0.f, 0.f, 0.f, 0.f};
#pragma unroll
  for (int i = 0; i < 4; ++i)
#pragma unroll
    for (int j = 0; j < 4; ++j) acc[i][j] = fz;

  const int srow = lane >> 2;  // row within 16-row chunk
  const int sk   = lane & 3;   // 16B slot within 64B row

  auto stage = [&](int buf, int k0) {
#pragma unroll
    for (int r = 0; r < 2; ++r) {
      const int c      = wave * 2 + r;
      const int row    = c * 16 + srow;
      const int gchunk = sk ^ (row & 3);
      const bf16* ga = A + (size_t)(m0 + row) * K + k0 + gchunk * 8;
      const bf16* gb = B + (size_t)(n0 + row) * K + k0 + gchunk * 8;
      __builtin_amdgcn_global_load_lds((const AS1 void*)ga, (AS3 void*)(Asl + buf * 4096 + c * 512), 16, 0, 0);
      __builtin_amdgcn_global_load_lds((const AS1 void*)gb, (AS3 void*)(Bsl + buf * 4096 + c * 512), 16, 0, 0);
    }
  };

  const int nk = K >> 5;
  stage(0, 0);
  for (int it = 0; it < nk; ++it) {
    __syncthreads();  // drains loads staged for THIS iter; buf[1-cur] readers done
    if (it + 1 < nk) stage((it + 1) & 1, (it + 1) << 5);
    const bf16* As = Asl + (it & 1) * 4096;
    const bf16* Bs = Bsl + (it & 1) * 4096;

    bf16x8 af[4], bfr[4];
#pragma unroll
    for (int i = 0; i < 4; ++i) {
      const int r = wr * 64 + i * 16 + col;
      af[i] = *(const bf16x8*)&As[r * 32 + ((quad ^ (col & 3)) * 8)];
    }
#pragma unroll
    for (int j = 0; j < 4; ++j) {
      const int r = wc * 64 + j * 16 + col;
      bfr[j] = *(const bf16x8*)&Bs[r * 32 + ((quad ^ (col & 3)) * 8)];
    }
#pragma unroll
    for (int i = 0; i < 4; ++i)
#pragma unroll
      for (int j = 0; j < 4; ++j)
        acc[i][j] = __builtin_amdgcn_mfma_f32_16x16x32_bf16(af[i], bfr[j], acc[i][j], 0, 0, 0);
  }

#pragma unroll
  for (int i = 0; i < 4; ++i) {
#pragma unroll
    for (int j = 0; j < 4; ++j) {
      const int gm0 = m0 + wr * 64 + i * 16 + quad * 4;
      const int gn  = n0 + wc * 64 + j * 16 + col;
#pragma unroll
      for (int r = 0; r < 4; ++r) {
        const size_t idx = (size_t)(gm0 + r) * N + gn;
        if (OUTF32) Cf[idx] = acc[i][j][r] * scale;
        else        Cb[idx] = (bf16)(acc[i][j][r] * scale);
      }
    }
  }
}

// fused Q/K/V projection: blockIdx.z selects weight/output
__global__ __launch_bounds__(256, 2)
void gemm_qkv(const bf16* __restrict__ A, const bf16* __restrict__ Wq,
              const bf16* __restrict__ Wk, const bf16* __restrict__ Wv,
              bf16* Qo, bf16* Ko, bf16* Vo, float qscale) {
  __shared__ bf16 Asl[2 * 4096];
  __shared__ bf16 Bsl[2 * 4096];
  const bf16* B; bf16* C; float sc = 1.0f;
  if (blockIdx.z == 0)      { B = Wq; C = Qo; sc = qscale; }
  else if (blockIdx.z == 1) { B = Wk; C = Ko; }
  else                      { B = Wv; C = Vo; }
  gemm_body<0>(A, B, nullptr, C, 8192, 1024, 1024, sc, Asl, Bsl);
}

__global__ __launch_bounds__(256, 2)
void gemm_o(const bf16* __restrict__ A, const bf16* __restrict__ W, float* __restrict__ C) {
  __shared__ bf16 Asl[2 * 4096];
  __shared__ bf16 Bsl[2 * 4096];
  gemm_body<1>(A, W, C, nullptr, 8192, 1024, 1024, 1.0f, Asl, Bsl);
}

// ---------------- flash causal attention, S^T formulation + K/V double-buffer ------
// Q pre-scaled by 0.125*log2(e). Vt: [(b*1024+n), t]. Block = 4 waves, Q-tile 64,
// t-tile 64. One barrier per t-tile; prefetch of tile tt+1 issued at iter top.
__global__ __launch_bounds__(256, 4)
void attn_flash(const bf16* __restrict__ Q, const bf16* __restrict__ K,
                const bf16* __restrict__ Vt, bf16* __restrict__ Y) {
  __shared__ bf16 Qs[64 * 64];
  __shared__ bf16 Ksb[2][64 * 64];
  __shared__ bf16 Vsb[2][64 * 64];
  // LDS total = 8K + 16K + 16K = 40960 B -> exactly 4 blocks/CU

  const int tid  = threadIdx.x;
  const int lane = tid & 63, wave = tid >> 6;
  const int quad = lane >> 4, col = lane & 15;
  const int qt = 31 - blockIdx.x;  // longest blocks first
  const int h  = blockIdx.y;
  const int b  = blockIdx.z;
  const int q0 = qt * 64;
  const int hc = h * 64;
  const size_t rowBase = (size_t)b * SQLEN;

  const int srow8 = lane >> 3;
  const int sch   = lane & 7;
  const int gch   = sch ^ srow8;   // XOR-8 swizzled global chunk
  const int a7    = col & 7;

  auto stageKV = [&](int buf, int t0) {
#pragma unroll
    for (int i = 0; i < 2; ++i) {
      const int c  = wave * 2 + i;
      const int rr = c * 8 + srow8;
      const bf16* gk = K + (rowBase + t0 + rr) * EMB + hc + gch * 8;
      const bf16* gv = Vt + ((size_t)(b * EMB + hc + rr)) * SQLEN + t0 + gch * 8;
      __builtin_amdgcn_global_load_lds((const AS1 void*)gk, (AS3 void*)(&Ksb[buf][c * 512]), 16, 0, 0);
      __builtin_amdgcn_global_load_lds((const AS1 void*)gv, (AS3 void*)(&Vsb[buf][c * 512]), 16, 0, 0);
    }
  };

  // ---- prologue: stage Q + first K/V tile ----
#pragma unroll
  for (int i = 0; i < 2; ++i) {
    const int c  = wave * 2 + i;
    const int rr = c * 8 + srow8;
    const bf16* g = Q + (rowBase + q0 + rr) * EMB + hc + gch * 8;
    __builtin_amdgcn_global_load_lds((const AS1 void*)g, (AS3 void*)(&Qs[c * 512]), 16, 0, 0);
  }
  stageKV(0, 0);
  __syncthreads();
  const bf16x8 qf0 = *(const bf16x8*)&Qs[(wave * 16 + col) * 64 + ((quad ^ a7) * 8)];
  const bf16x8 qf1 = *(const bf16x8*)&Qs[(wave * 16 + col) * 64 + (((quad ^ 4) ^ a7) * 8)];

  float m_i = -INFINITY, l_i = 0.f;
  f32x4 o[4];
  const f32x4 fz = {0.f, 0.f, 0.f, 0.f};
#pragma unroll
  for (int dd = 0; dd < 4; ++dd) o[dd] = fz;

  for (int tt = 0; tt <= qt; ++tt) {
    const int cur = tt & 1;
    if (tt < qt) stageKV(cur ^ 1, (tt + 1) * 64);  // in flight across this iter
    const bf16* Ks = Ksb[cur];
    const bf16* Vs = Vsb[cur];

    // ---- S^T slabs ----
    f32x4 s[4];
#pragma unroll
    for (int sl = 0; sl < 4; ++sl) {
      const bf16x8 kf0 = *(const bf16x8*)&Ks[(sl * 16 + col) * 64 + ((quad ^ a7) * 8)];
      const bf16x8 kf1 = *(const bf16x8*)&Ks[(sl * 16 + col) * 64 + (((quad ^ 4) ^ a7) * 8)];
      f32x4 z = fz;
      z = __builtin_amdgcn_mfma_f32_16x16x32_bf16(kf0, qf0, z, 0, 0, 0);
      s[sl] = __builtin_amdgcn_mfma_f32_16x16x32_bf16(kf1, qf1, z, 0, 0, 0);
    }

    if (tt == qt) {  // diagonal: mask t_local > q_local
      const int qloc = wave * 16 + col;
#pragma unroll
      for (int sl = 0; sl < 4; ++sl)
#pragma unroll
        for (int r = 0; r < 4; ++r)
          if (sl * 16 + quad * 4 + r > qloc) s[sl][r] = -INFINITY;
    }

    // ---- online softmax, exp2 domain, per-lane ----
    float mx = s[0][0];
#pragma unroll
    for (int sl = 0; sl < 4; ++sl)
#pragma unroll
      for (int r = 0; r < 4; ++r) mx = fmaxf(mx, s[sl][r]);
    mx = fmaxf(mx, __shfl_xor(mx, 16));
    mx = fmaxf(mx, __shfl_xor(mx, 32));
    const float mnew  = fmaxf(m_i, mx);
    const float alpha = __builtin_amdgcn_exp2f(m_i - mnew);
    float rs = 0.f;
    bf16x4 pb[4];
#pragma unroll
    for (int sl = 0; sl < 4; ++sl)
#pragma unroll
      for (int r = 0; r < 4; ++r) {
        const float p = __builtin_amdgcn_exp2f(s[sl][r] - mnew);
        rs += p;
        pb[sl][r] = (bf16)p;
      }
    rs += __shfl_xor(rs, 16);
    rs += __shfl_xor(rs, 32);
    l_i = l_i * alpha + rs;
    m_i = mnew;
#pragma unroll
    for (int dd = 0; dd < 4; ++dd) o[dd] *= alpha;

    // ---- O^T += V^T P^T (P straight from registers; k16 MFMA) ----
#pragma unroll
    for (int sl = 0; sl < 4; ++sl) {
      const s16x4 pf = __builtin_bit_cast(s16x4, pb[sl]);
      const int cch  = 2 * sl + (quad >> 1);
      const int half = quad & 1;
#pragma unroll
      for (int dd = 0; dd < 4; ++dd) {
        const int row = dd * 16 + col;
        const bf16x4 vb = *(const bf16x4*)&Vs[row * 64 + ((cch ^ a7) * 8) + half * 4];
        o[dd] = __builtin_amdgcn_mfma_f32_16x16x16bf16_1k(
            __builtin_bit_cast(s16x4, vb), pf, o[dd], 0, 0, 0);
      }
    }
    __syncthreads();  // drains prefetch; separates buffer reuse across iters
  }

  // ---- epilogue: O^T/l -> per-wave transpose in (dead) Ksb storage -> store ----
  const float rl = __builtin_amdgcn_rcpf(l_i);
  bf16* Ot = &Ksb[0][0] + wave * 1152;  // 16 rows x 72 stride, per-wave private
#pragma unroll
  for (int dd = 0; dd < 4; ++dd) {
    bf16x4 ob;
#pragma unroll
    for (int r = 0; r < 4; ++r) ob[r] = (bf16)(o[dd][r] * rl);
    *(bf16x4*)&Ot[col * 72 + dd * 16 + quad * 4] = ob;
  }
  // same-wave write->read: ordered by lgkmcnt, no barrier needed
#pragma unroll
  for (int i = 0; i < 2; ++i) {
    const int row = i * 8 + srow8;
    const bf16x8 v = *(const bf16x8*)&Ot[row * 72 + sch * 8];
    *(bf16x8*)&Y[(rowBase + q0 + wave * 16 + row) * EMB + hc + sch * 8] = v;
  }
}

// ---------------- launcher ----------------
extern "C" void kernel_launch(void* const* d_in, const int* in_sizes, int n_in,
                              void* d_out, int out_size, void* d_ws, size_t ws_size,
                              hipStream_t stream) {
  const float* x  = (const float*)d_in[0];
  const float* Wq = (const float*)d_in[1];
  const float* Wk = (const float*)d_in[2];
  const float* Wv = (const float*)d_in[3];
  const float* Wo = (const float*)d_in[4];
  float* out = (float*)d_out;

  const size_t ME = 8192ull * 1024ull;
  const size_t WE = 1024ull * 1024ull;
  bf16* ws  = (bf16*)d_ws;
  bf16* xb  = ws;
  bf16* wqb = xb + ME;
  bf16* wkb = wqb + WE;
  bf16* wvb = wkb + WE;
  bf16* wob = wvb + WE;
  bf16* Qb  = wob + WE;
  bf16* Kb  = Qb + ME;
  bf16* Vb  = Kb + ME;
  bf16* Yb  = Vb + ME;   // 92.3 MB total
  bf16* Vtb = xb;        // Vt aliases xb (dead after QKV GEMM)

  cvt_f32_bf16<<<(int)(ME / 8 / 256), 256, 0, stream>>>(x, xb, (int)(ME / 8));
  cvt_w4<<<dim3((int)(WE / 8 / 256), 4), 256, 0, stream>>>(Wq, Wk, Wv, Wo, wqb, wkb, wvb, wob, (int)(WE / 8));

  const float qscale = 0.125f * 1.4426950408889634f;  // fold 1/sqrt(64) and log2(e)
  gemm_qkv<<<dim3(64, 8, 3), 256, 0, stream>>>(xb, wqb, wkb, wvb, Qb, Kb, Vb, qscale);

  transpose_v<<<dim3(32, 16, 4), 256, 0, stream>>>(Vb, Vtb);
  attn_flash<<<dim3(32, 16, 4), 256, 0, stream>>>(Qb, Kb, Vtb, Yb);

  gemm_o<<<dim3(64, 8), 256, 0, stream>>>(Yb, wob, out);
}